// Round 13
// baseline (1367.662 us; speedup 1.0000x reference)
//
#include <hip/hip_runtime.h>
#include <hip/hip_fp16.h>

#define NN 100000
#define NE 3200000

// ---------- fp16 pack/unpack helpers ----------
__device__ inline unsigned pkh(float a, float b) {
  __half2 h;
  h.x = __float2half(a);
  h.y = __float2half(b);
  unsigned u;
  __builtin_memcpy(&u, &h, 4);
  return u;
}
__device__ inline float2 uph(unsigned u) {
  __half2 h;
  __builtin_memcpy(&h, &u, 4);
  return __half22float2(h);
}
__device__ inline float h1f(unsigned short v) {
  __half h;
  __builtin_memcpy(&h, &v, 2);
  return __half2float(h);
}
__device__ inline unsigned short f1h(float f) {
  __half h = __float2half(f);
  unsigned short u;
  __builtin_memcpy(&u, &h, 2);
  return u;
}

// ===================== CSR build =====================
__global__ __launch_bounds__(256) void count_kernel(const int* __restrict__ dst,
                                                    int* __restrict__ cnt) {
  int stride = gridDim.x * 256;
  for (int e = blockIdx.x * 256 + threadIdx.x; e < NE; e += stride)
    atomicAdd(&cnt[dst[e]], 1);
}

// single-block exclusive scan over NN counts -> rowptr[0..NN]; ofs=running copy
__global__ __launch_bounds__(1024) void scan_kernel(const int* __restrict__ cnt,
                                                    int* __restrict__ rowptr,
                                                    int* __restrict__ ofs) {
  __shared__ int bsum[1024];
  int tid = threadIdx.x;
  const int CH = (NN + 1023) / 1024;
  int lo = tid * CH, hi = lo + CH < NN ? lo + CH : NN;
  if (lo > NN) lo = NN;
  if (hi < lo) hi = lo;
  int s = 0;
  for (int i = lo; i < hi; i++) s += cnt[i];
  bsum[tid] = s;
  __syncthreads();
  for (int off = 1; off < 1024; off <<= 1) {
    int v = bsum[tid];
    int u = (tid >= off) ? bsum[tid - off] : 0;
    __syncthreads();
    bsum[tid] = v + u;
    __syncthreads();
  }
  int pre = (tid == 0) ? 0 : bsum[tid - 1];
  for (int i = lo; i < hi; i++) {
    int cv = cnt[i];
    rowptr[i] = pre;
    ofs[i] = pre;
    pre += cv;
  }
  if (tid == 1023) rowptr[NN] = pre;
}

// packed scatter, single 16B record (src embedded via stolen ea6 mantissa bit)
// + fused layer-1 message stream:
//   erec[pos] = uint4{ pkh(ea0,ea1), pkh(ea2,ea3), pkh(ea4,ea5),
//                      (f1h(ea6)&0xFFFE) | (src>>16) | ((src&0xFFFF)<<16) }
//   msg1[pos] = relu(x[src,:2] + ea@el1w + el1b) as float2   (fp32 inputs)
__global__ __launch_bounds__(256) void scatter2e_kernel(
    const int* __restrict__ src, const int* __restrict__ dst,
    const float* __restrict__ ea, int* __restrict__ ofs,
    uint4* __restrict__ erec, const float* __restrict__ x,
    const float* __restrict__ elw, const float* __restrict__ elb,
    float* __restrict__ msg1) {
  float w0[7], w1r[7];
#pragma unroll
  for (int k = 0; k < 7; k++) { w0[k] = elw[k * 2]; w1r[k] = elw[k * 2 + 1]; }
  float b0 = elb[0], b1 = elb[1];
  int stride = gridDim.x * 256;
  for (int e = blockIdx.x * 256 + threadIdx.x; e < NE; e += stride) {
    int sn = src[e];
    int pos = atomicAdd(&ofs[dst[e]], 1);
    float av[7];
#pragma unroll
    for (int k = 0; k < 7; k++) av[k] = ea[e * 7 + k];
    uint4 r;
    r.x = pkh(av[0], av[1]);
    r.y = pkh(av[2], av[3]);
    r.z = pkh(av[4], av[5]);
    r.w = ((unsigned)f1h(av[6]) & 0xFFFEu) | ((unsigned)sn >> 16) |
          (((unsigned)sn & 0xFFFFu) << 16);
    erec[pos] = r;
    float m0 = b0, m1 = b1;
#pragma unroll
    for (int k = 0; k < 7; k++) {
      m0 = fmaf(av[k], w0[k], m0);
      m1 = fmaf(av[k], w1r[k], m1);
    }
    m0 = fmaxf(m0 + x[sn * 2 + 0], 0.f);
    m1 = fmaxf(m1 + x[sn * 2 + 1], 0.f);
    float2 mv; mv.x = m0; mv.y = m1;
    ((float2*)msg1)[pos] = mv;
  }
}

// slim scatter: sorted edge ids only
__global__ __launch_bounds__(256) void scatter1_kernel(
    const int* __restrict__ dst, int* __restrict__ ofs, int* __restrict__ eid_s) {
  int stride = gridDim.x * 256;
  for (int e = blockIdx.x * 256 + threadIdx.x; e < NE; e += stride) {
    int pos = atomicAdd(&ofs[dst[e]], 1);
    eid_s[pos] = e;
  }
}

// ============ layer 1 (packed tier): segment-sum of precomputed msg1 =========
__global__ __launch_bounds__(256) void l1sum_kernel(
    const int* __restrict__ rowptr, const float* __restrict__ msg1,
    float* __restrict__ agg) {
  int stride = gridDim.x * 256;
  for (int n = blockIdx.x * 256 + threadIdx.x; n < NN; n += stride) {
    int r0 = rowptr[n], r1 = rowptr[n + 1];
    float a0 = 0.f, a1 = 0.f;
    const float2* mp = (const float2*)msg1;
    for (int i = r0; i < r1; i++) {
      float2 v = mp[i];
      a0 += v.x;
      a1 += v.y;
    }
    agg[n * 2 + 0] = a0;
    agg[n * 2 + 1] = a1;
  }
}

// =========== layer 1 slim-tier aggregate (thread per node, eid CSR) ==========
__global__ __launch_bounds__(256) void l1agg_kernel(
    const int* __restrict__ rowptr, const int* __restrict__ eid_s,
    const int* __restrict__ src, const float* __restrict__ ea,
    const float* __restrict__ x, const float* __restrict__ elw,
    const float* __restrict__ elb, float* __restrict__ agg) {
  float w0[7], w1r[7];
#pragma unroll
  for (int k = 0; k < 7; k++) { w0[k] = elw[k * 2]; w1r[k] = elw[k * 2 + 1]; }
  float b0 = elb[0], b1 = elb[1];
  int stride = gridDim.x * 256;
  for (int n = blockIdx.x * 256 + threadIdx.x; n < NN; n += stride) {
    int r0 = rowptr[n], r1 = rowptr[n + 1];
    float a0 = 0.f, a1 = 0.f;
    for (int i = r0; i < r1; i++) {
      int e = eid_s[i];
      int sn = src[e];
      float m0 = b0, m1 = b1;
#pragma unroll
      for (int k = 0; k < 7; k++) {
        float a = ea[e * 7 + k];
        m0 = fmaf(a, w0[k], m0);
        m1 = fmaf(a, w1r[k], m1);
      }
      m0 = fmaxf(m0 + x[sn * 2 + 0], 0.f);
      m1 = fmaxf(m1 + x[sn * 2 + 1], 0.f);
      a0 += m0; a1 += m1;
    }
    agg[n * 2 + 0] = a0;
    agg[n * 2 + 1] = a1;
  }
}

#define PROJH2(m, u) do { \
  float2 q0 = uph((u).x), q1 = uph((u).y), q2 = uph((u).z); \
  float e6 = h1f((unsigned short)((u).w & 0xFFFEu)); \
  m = bel; \
  m = fmaf(q0.x, wel[0], m); m = fmaf(q0.y, wel[1], m); \
  m = fmaf(q1.x, wel[2], m); m = fmaf(q1.y, wel[3], m); \
  m = fmaf(q2.x, wel[4], m); m = fmaf(q2.y, wel[5], m); \
  m = fmaf(e6, wel[6], m); } while (0)

#define SRCOF(u) ((int)((((u).w & 1u) << 16) | ((u).w >> 16)))

// ====== layers 2/3 fused, 16B records w/ embedded src, 4-deep pipeline =======
__global__ __launch_bounds__(256) void gine64h_kernel(
    const int* __restrict__ rowptr, const uint4* __restrict__ erec,
    const float* __restrict__ xin, const unsigned short* __restrict__ xh,
    const float* __restrict__ elw, const float* __restrict__ elb,
    const float* __restrict__ w1, const float* __restrict__ b1,
    const float* __restrict__ eps_p, float* __restrict__ tbuf,
    float* __restrict__ stats) {
  __shared__ float wl[64 * 64];
  __shared__ float hb[4][64];
  __shared__ float red[256];
  int tid = threadIdx.x, lane = tid & 63, wv = tid >> 6;
  for (int i2 = tid; i2 < 64 * 64; i2 += 256) wl[i2] = w1[i2];
  float wel[7];
#pragma unroll
  for (int k = 0; k < 7; k++) wel[k] = elw[k * 64 + lane];
  float bel = elb[lane], b1c = b1[lane];
  float ep = 1.0f + *eps_p;
  float s = 0.f, ss = 0.f;
  __syncthreads();
  const unsigned short* xl = xh + lane;
  int nw = gridDim.x * 4;
  for (int n = blockIdx.x * 4 + wv; n < NN; n += nw) {
    int r0 = rowptr[n], r1 = rowptr[n + 1];
    float acc = 0.f;
    int i = r0;
    int rem = r1 - r0;
    if (rem >= 4) {
      uint4 u0 = erec[i], u1 = erec[i + 1], u2 = erec[i + 2], u3 = erec[i + 3];
      while (true) {
        // decode srcs (2 VALU each) and issue 4 independent gathers
        int s0 = SRCOF(u0), s1 = SRCOF(u1), s2 = SRCOF(u2), s3 = SRCOF(u3);
        float g0 = h1f(xl[s0 * 64]);
        float g1 = h1f(xl[s1 * 64]);
        float g2 = h1f(xl[s2 * 64]);
        float g3 = h1f(xl[s3 * 64]);
        i += 4; rem -= 4;
        bool more = rem >= 4;
        int ip = more ? i : r0;  // dummy (valid) address when finishing
        // prefetch next group's records while gathers are in flight
        uint4 v0 = erec[ip], v1 = erec[ip + 1], v2 = erec[ip + 2], v3 = erec[ip + 3];
        // edge projections (independent of gathers)
        float m0, m1, m2, m3;
        PROJH2(m0, u0); PROJH2(m1, u1); PROJH2(m2, u2); PROJH2(m3, u3);
        acc += fmaxf(m0 + g0, 0.f);
        acc += fmaxf(m1 + g1, 0.f);
        acc += fmaxf(m2 + g2, 0.f);
        acc += fmaxf(m3 + g3, 0.f);
        u0 = v0; u1 = v1; u2 = v2; u3 = v3;
        if (!more) break;
      }
    }
    for (; i < r1; i++) {  // tail (0..3 edges)
      uint4 u = erec[i];
      int sn = SRCOF(u);
      float m;
      PROJH2(m, u);
      m += h1f(xl[sn * 64]);
      acc += fmaxf(m, 0.f);
    }
    float h = ep * xin[n * 64 + lane] + acc;
    hb[wv][lane] = h;  // same-wave LDS exchange (in-order DS pipe)
    float t = b1c;
#pragma unroll
    for (int k = 0; k < 64; k++) t = fmaf(hb[wv][k], wl[k * 64 + lane], t);
    tbuf[n * 64 + lane] = t;
    s += t;
    ss += t * t;
  }
  double* dsum = (double*)stats;
  red[tid] = s;
  __syncthreads();
  if (tid < 64) unsafeAtomicAdd(&dsum[tid], (double)(red[tid] + red[tid + 64] + red[tid + 128] + red[tid + 192]));
  __syncthreads();
  red[tid] = ss;
  __syncthreads();
  if (tid < 64) unsafeAtomicAdd(&dsum[64 + tid], (double)(red[tid] + red[tid + 64] + red[tid + 128] + red[tid + 192]));
}

// ====== layers 2/3 slim-tier (eid CSR, unpipelined — fallback only) ==========
__global__ __launch_bounds__(256) void gine64s_kernel(
    const int* __restrict__ rowptr, const int* __restrict__ eid_s,
    const int* __restrict__ src, const float* __restrict__ ea,
    const float* __restrict__ xin, const float* __restrict__ elw,
    const float* __restrict__ elb, const float* __restrict__ w1,
    const float* __restrict__ b1, const float* __restrict__ eps_p,
    float* __restrict__ tbuf, float* __restrict__ stats) {
  __shared__ float wl[64 * 64];
  __shared__ float hb[4][64];
  __shared__ float red[256];
  int tid = threadIdx.x, lane = tid & 63, wv = tid >> 6;
  for (int i = tid; i < 64 * 64; i += 256) wl[i] = w1[i];
  float wel[7];
#pragma unroll
  for (int k = 0; k < 7; k++) wel[k] = elw[k * 64 + lane];
  float bel = elb[lane], b1c = b1[lane];
  float ep = 1.0f + *eps_p;
  float s = 0.f, ss = 0.f;
  __syncthreads();
  int nw = gridDim.x * 4;
  for (int n = blockIdx.x * 4 + wv; n < NN; n += nw) {
    int r0 = rowptr[n], r1 = rowptr[n + 1];
    float acc = 0.f;
    for (int i = r0; i < r1; i++) {
      int e = eid_s[i];
      int sn = src[e];
      float m = bel;
#pragma unroll
      for (int k = 0; k < 7; k++) m = fmaf(ea[e * 7 + k], wel[k], m);
      m += xin[sn * 64 + lane];
      acc += fmaxf(m, 0.f);
    }
    float h = ep * xin[n * 64 + lane] + acc;
    hb[wv][lane] = h;
    float t = b1c;
#pragma unroll
    for (int k = 0; k < 64; k++) t = fmaf(hb[wv][k], wl[k * 64 + lane], t);
    tbuf[n * 64 + lane] = t;
    s += t;
    ss += t * t;
  }
  double* dsum = (double*)stats;
  red[tid] = s;
  __syncthreads();
  if (tid < 64) unsafeAtomicAdd(&dsum[tid], (double)(red[tid] + red[tid + 64] + red[tid + 128] + red[tid + 192]));
  __syncthreads();
  red[tid] = ss;
  __syncthreads();
  if (tid < 64) unsafeAtomicAdd(&dsum[64 + tid], (double)(red[tid] + red[tid + 64] + red[tid + 128] + red[tid + 192]));
}

// ===================== legacy (fallback tier B) kernels ======================
__global__ __launch_bounds__(256) void edge1_kernel(
    const float* __restrict__ x, const float* __restrict__ ea,
    const int* __restrict__ src, const int* __restrict__ dst,
    const float* __restrict__ elw, const float* __restrict__ elb,
    float* __restrict__ agg) {
  float w0[7], w1[7];
#pragma unroll
  for (int k = 0; k < 7; k++) { w0[k] = elw[k * 2]; w1[k] = elw[k * 2 + 1]; }
  float b0 = elb[0], b1 = elb[1];
  int stride = gridDim.x * 256;
  for (int e = blockIdx.x * 256 + threadIdx.x; e < NE; e += stride) {
    int s = src[e], d = dst[e];
    float m0 = b0, m1 = b1;
#pragma unroll
    for (int k = 0; k < 7; k++) {
      float a = ea[e * 7 + k];
      m0 = fmaf(a, w0[k], m0);
      m1 = fmaf(a, w1[k], m1);
    }
    m0 = fmaxf(m0 + x[s * 2 + 0], 0.f);
    m1 = fmaxf(m1 + x[s * 2 + 1], 0.f);
    unsafeAtomicAdd(&agg[d * 2 + 0], m0);
    unsafeAtomicAdd(&agg[d * 2 + 1], m1);
  }
}

__global__ __launch_bounds__(256) void edge64_kernel(
    const float* __restrict__ xin, const float* __restrict__ ea,
    const int* __restrict__ src, const int* __restrict__ dst,
    const float* __restrict__ elw, const float* __restrict__ elb,
    float* __restrict__ agg) {
  int lane = threadIdx.x & 63;
  int wid = (blockIdx.x * 256 + threadIdx.x) >> 6;
  int nw = (gridDim.x * 256) >> 6;
  float w[7];
#pragma unroll
  for (int k = 0; k < 7; k++) w[k] = elw[k * 64 + lane];
  float b = elb[lane];
  for (int e = wid; e < NE; e += nw) {
    int eu = __builtin_amdgcn_readfirstlane(e);
    int s = src[eu];
    int d = dst[eu];
    float m = b;
#pragma unroll
    for (int k = 0; k < 7; k++) m = fmaf(ea[eu * 7 + k], w[k], m);
    m += xin[s * 64 + lane];
    m = fmaxf(m, 0.f);
    unsafeAtomicAdd(&agg[d * 64 + lane], m);
  }
}

__global__ __launch_bounds__(256) void nodeA64_kernel(
    const float* __restrict__ xin, float* __restrict__ tbuf,
    const float* __restrict__ w1, const float* __restrict__ b1,
    const float* __restrict__ eps_p, float* __restrict__ stats) {
  __shared__ float wl[64 * 64];
  __shared__ float hbuf[4][64];
  __shared__ float red[256];
  int tid = threadIdx.x;
  int c = tid & 63, nl = tid >> 6;
  for (int i = tid; i < 64 * 64; i += 256) wl[i] = w1[i];
  float ep = 1.0f + *eps_p;
  float bc = b1[c];
  float s = 0.f, ss = 0.f;
  __syncthreads();
  for (int n0 = blockIdx.x * 4; n0 < NN; n0 += gridDim.x * 4) {
    int n = n0 + nl;
    bool valid = n < NN;
    float h = 0.f;
    if (valid) h = ep * xin[n * 64 + c] + tbuf[n * 64 + c];
    hbuf[nl][c] = h;
    __syncthreads();
    if (valid) {
      float t = bc;
#pragma unroll
      for (int k = 0; k < 64; k++) t = fmaf(hbuf[nl][k], wl[k * 64 + c], t);
      tbuf[n * 64 + c] = t;
      s += t;
      ss += t * t;
    }
    __syncthreads();
  }
  double* dsum = (double*)stats;
  red[tid] = s;
  __syncthreads();
  if (tid < 64) unsafeAtomicAdd(&dsum[tid], (double)(red[tid] + red[tid + 64] + red[tid + 128] + red[tid + 192]));
  __syncthreads();
  red[tid] = ss;
  __syncthreads();
  if (tid < 64) unsafeAtomicAdd(&dsum[64 + tid], (double)(red[tid] + red[tid + 64] + red[tid + 128] + red[tid + 192]));
}

// ===================== shared node kernels ===================================
__global__ __launch_bounds__(256) void nodeA2_kernel(
    const float* __restrict__ x, const float* __restrict__ agg1,
    float* __restrict__ tbuf, const float* __restrict__ w1,
    const float* __restrict__ b1, const float* __restrict__ eps_p,
    float* __restrict__ stats) {
  __shared__ float red[256];
  int tid = threadIdx.x;
  int c = tid & 63, nl = tid >> 6;
  float wa = w1[c], wb = w1[64 + c], bc = b1[c];
  float ep = 1.0f + *eps_p;
  float s = 0.f, ss = 0.f;
  for (int n0 = blockIdx.x * 4; n0 < NN; n0 += gridDim.x * 4) {
    int n = n0 + nl;
    if (n < NN) {
      float h0 = ep * x[n * 2 + 0] + agg1[n * 2 + 0];
      float h1 = ep * x[n * 2 + 1] + agg1[n * 2 + 1];
      float t = fmaf(h1, wb, fmaf(h0, wa, bc));
      tbuf[n * 64 + c] = t;
      s += t;
      ss += t * t;
    }
  }
  double* dsum = (double*)stats;
  red[tid] = s;
  __syncthreads();
  if (tid < 64) unsafeAtomicAdd(&dsum[tid], (double)(red[tid] + red[tid + 64] + red[tid + 128] + red[tid + 192]));
  __syncthreads();
  red[tid] = ss;
  __syncthreads();
  if (tid < 64) unsafeAtomicAdd(&dsum[64 + tid], (double)(red[tid] + red[tid + 64] + red[tid + 128] + red[tid + 192]));
}

// --- node B with fused BN finalize: u=relu(BN(t)); out=relu(u@w2+b2)
// --- optionally emits fp16 copy of out (for next layer's gathers)
__global__ __launch_bounds__(256) void nodeB_kernel(
    const float* __restrict__ tin, float* __restrict__ outb,
    const float* __restrict__ w2, const float* __restrict__ b2,
    const float* __restrict__ stats, const float* __restrict__ g,
    const float* __restrict__ bt, unsigned short* __restrict__ xh) {
  __shared__ float wl[64 * 64];
  __shared__ float ubuf[4][64];
  __shared__ float scsh[128];
  int tid = threadIdx.x;
  int c = tid & 63, nl = tid >> 6;
  for (int i = tid; i < 64 * 64; i += 256) wl[i] = w2[i];
  if (tid < 64) {
    const double* ds = (const double*)stats;
    double m = ds[tid] / (double)NN;
    double v = ds[64 + tid] / (double)NN - m * m;
    float sc = g[tid] * (float)(1.0 / sqrt(v + 1e-5));
    scsh[tid] = sc;
    scsh[64 + tid] = bt[tid] - (float)m * sc;
  }
  float bc = b2[c];
  __syncthreads();
  float scale = scsh[c], shift = scsh[64 + c];
  for (int n0 = blockIdx.x * 4; n0 < NN; n0 += gridDim.x * 4) {
    int n = n0 + nl;
    bool valid = n < NN;
    float u = 0.f;
    if (valid) {
      float t = tin[n * 64 + c];
      u = fmaxf(fmaf(t, scale, shift), 0.f);
    }
    ubuf[nl][c] = u;
    __syncthreads();
    if (valid) {
      float o = bc;
#pragma unroll
      for (int k = 0; k < 64; k++) o = fmaf(ubuf[nl][k], wl[k * 64 + c], o);
      o = fmaxf(o, 0.f);
      outb[n * 64 + c] = o;
      if (xh) xh[n * 64 + c] = f1h(o);
    }
    __syncthreads();
  }
}

__global__ __launch_bounds__(256) void final_kernel(
    const float* __restrict__ xin, const float* __restrict__ regw,
    const float* __restrict__ regb, const float* __restrict__ endw,
    const float* __restrict__ endb, float* __restrict__ out) {
  __shared__ float wl[64 * 128];
  __shared__ float eb[256];
  int tid = threadIdx.x;
  int node = blockIdx.x * 256 + tid;
  bool valid = node < NN;
  float xr[64];
  if (valid) {
    const float4* xp = (const float4*)(xin + node * 64);
#pragma unroll
    for (int k4 = 0; k4 < 16; k4++) {
      float4 v = xp[k4];
      xr[k4 * 4 + 0] = v.x; xr[k4 * 4 + 1] = v.y;
      xr[k4 * 4 + 2] = v.z; xr[k4 * 4 + 3] = v.w;
    }
  }
  float y = 0.f;
  for (int ch = 0; ch < 4; ch++) {
    int j0 = ch * 125;
    __syncthreads();
    for (int idx = tid; idx < 64 * 125; idx += 256) {
      int k = idx / 125;
      int jl = idx - k * 125;
      wl[k * 128 + jl] = regw[k * 500 + j0 + jl];
    }
    if (tid < 125) { eb[tid] = regb[j0 + tid]; eb[128 + tid] = endw[j0 + tid]; }
    __syncthreads();
    if (valid) {
      int jl = 0;
      for (; jl + 4 <= 125; jl += 4) {
        float t0 = eb[jl], t1 = eb[jl + 1], t2 = eb[jl + 2], t3 = eb[jl + 3];
#pragma unroll
        for (int k = 0; k < 64; k++) {
          float4 w4 = *(const float4*)&wl[k * 128 + jl];
          float xv = xr[k];
          t0 = fmaf(xv, w4.x, t0);
          t1 = fmaf(xv, w4.y, t1);
          t2 = fmaf(xv, w4.z, t2);
          t3 = fmaf(xv, w4.w, t3);
        }
        t0 = t0 >= 0.f ? t0 : 0.01f * t0;
        t1 = t1 >= 0.f ? t1 : 0.01f * t1;
        t2 = t2 >= 0.f ? t2 : 0.01f * t2;
        t3 = t3 >= 0.f ? t3 : 0.01f * t3;
        y += t0 * eb[128 + jl] + t1 * eb[128 + jl + 1] + t2 * eb[128 + jl + 2] + t3 * eb[128 + jl + 3];
      }
      {
        float t = eb[124];
#pragma unroll
        for (int k = 0; k < 64; k++) t = fmaf(xr[k], wl[k * 128 + 124], t);
        t = t >= 0.f ? t : 0.01f * t;
        y += t * eb[128 + 124];
      }
    }
  }
  if (valid) out[node] = y + endb[0];
}

extern "C" void kernel_launch(void* const* d_in, const int* in_sizes, int n_in,
                              void* d_out, int out_size, void* d_ws, size_t ws_size,
                              hipStream_t stream) {
  const float* x    = (const float*)d_in[0];
  const float* ea   = (const float*)d_in[1];
  const int*   ei   = (const int*)d_in[2];
  const float* eps1 = (const float*)d_in[4];
  const float* el1w = (const float*)d_in[5];
  const float* el1b = (const float*)d_in[6];
  const float* n1w1 = (const float*)d_in[7];
  const float* n1b1 = (const float*)d_in[8];
  const float* n1g  = (const float*)d_in[9];
  const float* n1bt = (const float*)d_in[10];
  const float* n1w2 = (const float*)d_in[11];
  const float* n1b2 = (const float*)d_in[12];
  const float* eps2 = (const float*)d_in[13];
  const float* el2w = (const float*)d_in[14];
  const float* el2b = (const float*)d_in[15];
  const float* n2w1 = (const float*)d_in[16];
  const float* n2b1 = (const float*)d_in[17];
  const float* n2g  = (const float*)d_in[18];
  const float* n2bt = (const float*)d_in[19];
  const float* n2w2 = (const float*)d_in[20];
  const float* n2b2 = (const float*)d_in[21];
  const float* regw = (const float*)d_in[22];
  const float* regb = (const float*)d_in[23];
  const float* endw = (const float*)d_in[24];
  const float* endb = (const float*)d_in[25];
  const int* srcp = ei;
  const int* dstp = ei + NE;

  // ---- tier-A layout (float offsets) ----
  const size_t o_stats  = 0;          // 768 floats = 3 layers × 128 doubles
  const size_t o_cnt    = 768;        // NN ints (contiguous w/ stats: one memset)
  const size_t o_rowptr = 100768;     // NN+1 ints
  const size_t o_buf0   = 200832;     // N*64 floats; msg1 [E]float2 pre-layer-2
  const size_t o_buf1   = 6600832;    // N*64 floats
  const size_t o_xh     = 13000832;   // N*64 fp16 (= 3.2M floats)
  const size_t o_agg1   = 16200832;   // N*2 floats
  const size_t o_edat   = 16400832;   // packed: E uint4 | slim: E ints
  const size_t needA2 = (o_edat + (size_t)NE * 4) * 4;  // ~116.8 MB
  const size_t needA1 = (o_edat + (size_t)NE) * 4;      // ~78.4 MB
  const size_t needB  = (2 * 6600000 + 384) * 4;        // ~52.8 MB

  float* wsf = (float*)d_ws;

  if (ws_size >= needA1) {
    const bool packed = ws_size >= needA2;
    float* stats0 = wsf + o_stats;        // layer 1
    float* stats1 = wsf + o_stats + 256;  // layer 2
    float* stats2 = wsf + o_stats + 512;  // layer 3
    int* cnt     = (int*)(wsf + o_cnt);
    int* rowptr  = (int*)(wsf + o_rowptr);
    float* buf0  = wsf + o_buf0;
    float* buf1  = wsf + o_buf1;
    unsigned short* xh = (unsigned short*)(wsf + o_xh);
    float* agg1  = wsf + o_agg1;
    uint4* erec  = (uint4*)(wsf + o_edat);
    float* msg1  = buf0;  // [E]float2 == N*64 floats exactly; free until layer 2

    // ---- one memset covers stats(3 layers) + cnt ----
    hipMemsetAsync(wsf, 0, (768 + NN) * sizeof(float), stream);

    // ---- CSR build (once, shared by all 3 layers) ----
    count_kernel<<<4096, 256, 0, stream>>>(dstp, cnt);
    scan_kernel<<<1, 1024, 0, stream>>>(cnt, rowptr, cnt);
    if (packed)
      scatter2e_kernel<<<4096, 256, 0, stream>>>(srcp, dstp, ea, cnt, erec,
                                                 x, el1w, el1b, msg1);
    else
      scatter1_kernel<<<4096, 256, 0, stream>>>(dstp, cnt, (int*)(wsf + o_edat));

    // ---- layer 1 ----
    if (packed)
      l1sum_kernel<<<391, 256, 0, stream>>>(rowptr, msg1, agg1);
    else
      l1agg_kernel<<<391, 256, 0, stream>>>(rowptr, (const int*)(wsf + o_edat),
                                            srcp, ea, x, el1w, el1b, agg1);
    nodeA2_kernel<<<2048, 256, 0, stream>>>(x, agg1, buf1, n1w1, n1b1, eps1, stats0);
    nodeB_kernel<<<2048, 256, 0, stream>>>(buf1, buf1, n1w2, n1b2, stats0,
                                           n1g, n1bt, packed ? xh : nullptr);

    // ---- layers 2,3 (shared weights) ----
    if (packed) {
      gine64h_kernel<<<4096, 256, 0, stream>>>(rowptr, erec, buf1, xh,
                                               el2w, el2b, n2w1, n2b1, eps2,
                                               buf0, stats1);
      nodeB_kernel<<<2048, 256, 0, stream>>>(buf0, buf0, n2w2, n2b2, stats1,
                                             n2g, n2bt, xh);
      gine64h_kernel<<<4096, 256, 0, stream>>>(rowptr, erec, buf0, xh,
                                               el2w, el2b, n2w1, n2b1, eps2,
                                               buf1, stats2);
      nodeB_kernel<<<2048, 256, 0, stream>>>(buf1, buf1, n2w2, n2b2, stats2,
                                             n2g, n2bt, nullptr);
      final_kernel<<<(NN + 255) / 256, 256, 0, stream>>>(buf1, regw, regb, endw,
                                                         endb, (float*)d_out);
    } else {
      float* cur = buf1;
      float* wrk = buf0;
      float* sl[2] = {stats1, stats2};
      for (int l = 0; l < 2; l++) {
        gine64s_kernel<<<4096, 256, 0, stream>>>(rowptr, (const int*)(wsf + o_edat),
                                                 srcp, ea, cur, el2w, el2b, n2w1,
                                                 n2b1, eps2, wrk, sl[l]);
        nodeB_kernel<<<2048, 256, 0, stream>>>(wrk, wrk, n2w2, n2b2, sl[l],
                                               n2g, n2bt, nullptr);
        float* tmp = cur; cur = wrk; wrk = tmp;
      }
      final_kernel<<<(NN + 255) / 256, 256, 0, stream>>>(cur, regw, regb, endw,
                                                         endb, (float*)d_out);
    }
    return;
  }

  // ================= fallback tier B (round-1 proven path) =================
  if (ws_size < needB) return;
  const size_t BUF = 6600000;
  float* buf0 = (float*)d_ws;
  float* buf1 = buf0 + BUF;
  float* stats = buf1 + BUF;

  float* t1 = buf1;
  float* agg1 = buf1 + NN * 64;
  hipMemsetAsync(agg1, 0, NN * 2 * sizeof(float), stream);
  hipMemsetAsync(stats, 0, 128 * sizeof(double), stream);
  edge1_kernel<<<2048, 256, 0, stream>>>(x, ea, srcp, dstp, el1w, el1b, agg1);
  nodeA2_kernel<<<2048, 256, 0, stream>>>(x, agg1, t1, n1w1, n1b1, eps1, stats);
  nodeB_kernel<<<2048, 256, 0, stream>>>(t1, buf1, n1w2, n1b2, stats, n1g, n1bt,
                                         nullptr);

  float* cur = buf1;
  float* wrk = buf0;
  for (int l = 0; l < 2; l++) {
    hipMemsetAsync(wrk, 0, NN * 64 * sizeof(float), stream);
    hipMemsetAsync(stats, 0, 128 * sizeof(double), stream);
    edge64_kernel<<<2048, 256, 0, stream>>>(cur, ea, srcp, dstp, el2w, el2b, wrk);
    nodeA64_kernel<<<2048, 256, 0, stream>>>(cur, wrk, n2w1, n2b1, eps2, stats);
    nodeB_kernel<<<2048, 256, 0, stream>>>(wrk, wrk, n2w2, n2b2, stats, n2g, n2bt,
                                           nullptr);
    float* tmp = cur; cur = wrk; wrk = tmp;
  }

  final_kernel<<<(NN + 255) / 256, 256, 0, stream>>>(cur, regw, regb, endw, endb,
                                                     (float*)d_out);
}

// Round 14
// 1314.846 us; speedup vs baseline: 1.0402x; 1.0402x over previous
//
#include <hip/hip_runtime.h>
#include <hip/hip_fp16.h>

#define NN 100000
#define NE 3200000

// ---------- fp16 pack/unpack helpers ----------
__device__ inline unsigned pkh(float a, float b) {
  __half2 h;
  h.x = __float2half(a);
  h.y = __float2half(b);
  unsigned u;
  __builtin_memcpy(&u, &h, 4);
  return u;
}
__device__ inline float2 uph(unsigned u) {
  __half2 h;
  __builtin_memcpy(&h, &u, 4);
  return __half22float2(h);
}
__device__ inline float h1f(unsigned short v) {
  __half h;
  __builtin_memcpy(&h, &v, 2);
  return __half2float(h);
}
__device__ inline unsigned short f1h(float f) {
  __half h = __float2half(f);
  unsigned short u;
  __builtin_memcpy(&u, &h, 2);
  return u;
}

// ===================== CSR build =====================
__global__ __launch_bounds__(256) void count_kernel(const int* __restrict__ dst,
                                                    int* __restrict__ cnt) {
  int stride = gridDim.x * 256;
  for (int e = blockIdx.x * 256 + threadIdx.x; e < NE; e += stride)
    atomicAdd(&cnt[dst[e]], 1);
}

// single-block exclusive scan over NN counts -> rowptr[0..NN]; ofs=running copy
__global__ __launch_bounds__(1024) void scan_kernel(const int* __restrict__ cnt,
                                                    int* __restrict__ rowptr,
                                                    int* __restrict__ ofs) {
  __shared__ int bsum[1024];
  int tid = threadIdx.x;
  const int CH = (NN + 1023) / 1024;
  int lo = tid * CH, hi = lo + CH < NN ? lo + CH : NN;
  if (lo > NN) lo = NN;
  if (hi < lo) hi = lo;
  int s = 0;
  for (int i = lo; i < hi; i++) s += cnt[i];
  bsum[tid] = s;
  __syncthreads();
  for (int off = 1; off < 1024; off <<= 1) {
    int v = bsum[tid];
    int u = (tid >= off) ? bsum[tid - off] : 0;
    __syncthreads();
    bsum[tid] = v + u;
    __syncthreads();
  }
  int pre = (tid == 0) ? 0 : bsum[tid - 1];
  for (int i = lo; i < hi; i++) {
    int cv = cnt[i];
    rowptr[i] = pre;
    ofs[i] = pre;
    pre += cv;
  }
  if (tid == 1023) rowptr[NN] = pre;
}

// packed scatter, single 16B record (src embedded via stolen ea6 mantissa bit)
// + fused layer-1 message stream:
//   erec[pos] = uint4{ pkh(ea0,ea1), pkh(ea2,ea3), pkh(ea4,ea5),
//                      (f1h(ea6)&0xFFFE) | (src>>16) | ((src&0xFFFF)<<16) }
//   msg1[pos] = relu(x[src,:2] + ea@el1w + el1b) as float2   (fp32 inputs)
__global__ __launch_bounds__(256) void scatter2e_kernel(
    const int* __restrict__ src, const int* __restrict__ dst,
    const float* __restrict__ ea, int* __restrict__ ofs,
    uint4* __restrict__ erec, const float* __restrict__ x,
    const float* __restrict__ elw, const float* __restrict__ elb,
    float* __restrict__ msg1) {
  float w0[7], w1r[7];
#pragma unroll
  for (int k = 0; k < 7; k++) { w0[k] = elw[k * 2]; w1r[k] = elw[k * 2 + 1]; }
  float b0 = elb[0], b1 = elb[1];
  int stride = gridDim.x * 256;
  for (int e = blockIdx.x * 256 + threadIdx.x; e < NE; e += stride) {
    int sn = src[e];
    int pos = atomicAdd(&ofs[dst[e]], 1);
    float av[7];
#pragma unroll
    for (int k = 0; k < 7; k++) av[k] = ea[e * 7 + k];
    uint4 r;
    r.x = pkh(av[0], av[1]);
    r.y = pkh(av[2], av[3]);
    r.z = pkh(av[4], av[5]);
    r.w = ((unsigned)f1h(av[6]) & 0xFFFEu) | ((unsigned)sn >> 16) |
          (((unsigned)sn & 0xFFFFu) << 16);
    erec[pos] = r;
    float m0 = b0, m1 = b1;
#pragma unroll
    for (int k = 0; k < 7; k++) {
      m0 = fmaf(av[k], w0[k], m0);
      m1 = fmaf(av[k], w1r[k], m1);
    }
    m0 = fmaxf(m0 + x[sn * 2 + 0], 0.f);
    m1 = fmaxf(m1 + x[sn * 2 + 1], 0.f);
    float2 mv; mv.x = m0; mv.y = m1;
    ((float2*)msg1)[pos] = mv;
  }
}

// slim scatter: sorted edge ids only
__global__ __launch_bounds__(256) void scatter1_kernel(
    const int* __restrict__ dst, int* __restrict__ ofs, int* __restrict__ eid_s) {
  int stride = gridDim.x * 256;
  for (int e = blockIdx.x * 256 + threadIdx.x; e < NE; e += stride) {
    int pos = atomicAdd(&ofs[dst[e]], 1);
    eid_s[pos] = e;
  }
}

// ============ layer 1 (packed tier): segment-sum of precomputed msg1 =========
__global__ __launch_bounds__(256) void l1sum_kernel(
    const int* __restrict__ rowptr, const float* __restrict__ msg1,
    float* __restrict__ agg) {
  int stride = gridDim.x * 256;
  for (int n = blockIdx.x * 256 + threadIdx.x; n < NN; n += stride) {
    int r0 = rowptr[n], r1 = rowptr[n + 1];
    float a0 = 0.f, a1 = 0.f;
    const float2* mp = (const float2*)msg1;
    for (int i = r0; i < r1; i++) {
      float2 v = mp[i];
      a0 += v.x;
      a1 += v.y;
    }
    agg[n * 2 + 0] = a0;
    agg[n * 2 + 1] = a1;
  }
}

// =========== layer 1 slim-tier aggregate (thread per node, eid CSR) ==========
__global__ __launch_bounds__(256) void l1agg_kernel(
    const int* __restrict__ rowptr, const int* __restrict__ eid_s,
    const int* __restrict__ src, const float* __restrict__ ea,
    const float* __restrict__ x, const float* __restrict__ elw,
    const float* __restrict__ elb, float* __restrict__ agg) {
  float w0[7], w1r[7];
#pragma unroll
  for (int k = 0; k < 7; k++) { w0[k] = elw[k * 2]; w1r[k] = elw[k * 2 + 1]; }
  float b0 = elb[0], b1 = elb[1];
  int stride = gridDim.x * 256;
  for (int n = blockIdx.x * 256 + threadIdx.x; n < NN; n += stride) {
    int r0 = rowptr[n], r1 = rowptr[n + 1];
    float a0 = 0.f, a1 = 0.f;
    for (int i = r0; i < r1; i++) {
      int e = eid_s[i];
      int sn = src[e];
      float m0 = b0, m1 = b1;
#pragma unroll
      for (int k = 0; k < 7; k++) {
        float a = ea[e * 7 + k];
        m0 = fmaf(a, w0[k], m0);
        m1 = fmaf(a, w1r[k], m1);
      }
      m0 = fmaxf(m0 + x[sn * 2 + 0], 0.f);
      m1 = fmaxf(m1 + x[sn * 2 + 1], 0.f);
      a0 += m0; a1 += m1;
    }
    agg[n * 2 + 0] = a0;
    agg[n * 2 + 1] = a1;
  }
}

#define PROJH2(m, u) do { \
  float2 q0 = uph((u).x), q1 = uph((u).y), q2 = uph((u).z); \
  float e6 = h1f((unsigned short)((u).w & 0xFFFEu)); \
  m = bel; \
  m = fmaf(q0.x, wel[0], m); m = fmaf(q0.y, wel[1], m); \
  m = fmaf(q1.x, wel[2], m); m = fmaf(q1.y, wel[3], m); \
  m = fmaf(q2.x, wel[4], m); m = fmaf(q2.y, wel[5], m); \
  m = fmaf(e6, wel[6], m); } while (0)

#define SRCOF(u) ((int)((((u).w & 1u) << 16) | ((u).w >> 16)))

// ====== layers 2/3 fused, 16B records w/ embedded src, 4-deep pipeline =======
__global__ __launch_bounds__(256) void gine64h_kernel(
    const int* __restrict__ rowptr, const uint4* __restrict__ erec,
    const float* __restrict__ xin, const unsigned short* __restrict__ xh,
    const float* __restrict__ elw, const float* __restrict__ elb,
    const float* __restrict__ w1, const float* __restrict__ b1,
    const float* __restrict__ eps_p, float* __restrict__ tbuf,
    float* __restrict__ stats) {
  __shared__ float wl[64 * 64];
  __shared__ float hb[4][64];
  __shared__ float red[256];
  int tid = threadIdx.x, lane = tid & 63, wv = tid >> 6;
  for (int i2 = tid; i2 < 64 * 64; i2 += 256) wl[i2] = w1[i2];
  float wel[7];
#pragma unroll
  for (int k = 0; k < 7; k++) wel[k] = elw[k * 64 + lane];
  float bel = elb[lane], b1c = b1[lane];
  float ep = 1.0f + *eps_p;
  float s = 0.f, ss = 0.f;
  __syncthreads();
  const unsigned short* xl = xh + lane;
  int nw = gridDim.x * 4;
  for (int n = blockIdx.x * 4 + wv; n < NN; n += nw) {
    int r0 = rowptr[n], r1 = rowptr[n + 1];
    float acc = 0.f;
    int i = r0;
    int rem = r1 - r0;
    if (rem >= 4) {
      uint4 u0 = erec[i], u1 = erec[i + 1], u2 = erec[i + 2], u3 = erec[i + 3];
      while (true) {
        // decode srcs (2 VALU each) and issue 4 independent gathers
        int s0 = SRCOF(u0), s1 = SRCOF(u1), s2 = SRCOF(u2), s3 = SRCOF(u3);
        float g0 = h1f(xl[s0 * 64]);
        float g1 = h1f(xl[s1 * 64]);
        float g2 = h1f(xl[s2 * 64]);
        float g3 = h1f(xl[s3 * 64]);
        i += 4; rem -= 4;
        bool more = rem >= 4;
        int ip = more ? i : r0;  // dummy (valid) address when finishing
        // prefetch next group's records while gathers are in flight
        uint4 v0 = erec[ip], v1 = erec[ip + 1], v2 = erec[ip + 2], v3 = erec[ip + 3];
        // edge projections (independent of gathers)
        float m0, m1, m2, m3;
        PROJH2(m0, u0); PROJH2(m1, u1); PROJH2(m2, u2); PROJH2(m3, u3);
        acc += fmaxf(m0 + g0, 0.f);
        acc += fmaxf(m1 + g1, 0.f);
        acc += fmaxf(m2 + g2, 0.f);
        acc += fmaxf(m3 + g3, 0.f);
        u0 = v0; u1 = v1; u2 = v2; u3 = v3;
        if (!more) break;
      }
    }
    for (; i < r1; i++) {  // tail (0..3 edges)
      uint4 u = erec[i];
      int sn = SRCOF(u);
      float m;
      PROJH2(m, u);
      m += h1f(xl[sn * 64]);
      acc += fmaxf(m, 0.f);
    }
    float h = ep * xin[n * 64 + lane] + acc;
    hb[wv][lane] = h;  // same-wave LDS exchange (in-order DS pipe)
    float t = b1c;
#pragma unroll
    for (int k = 0; k < 64; k++) t = fmaf(hb[wv][k], wl[k * 64 + lane], t);
    tbuf[n * 64 + lane] = t;
    s += t;
    ss += t * t;
  }
  double* dsum = (double*)stats;
  red[tid] = s;
  __syncthreads();
  if (tid < 64) unsafeAtomicAdd(&dsum[tid], (double)(red[tid] + red[tid + 64] + red[tid + 128] + red[tid + 192]));
  __syncthreads();
  red[tid] = ss;
  __syncthreads();
  if (tid < 64) unsafeAtomicAdd(&dsum[64 + tid], (double)(red[tid] + red[tid + 64] + red[tid + 128] + red[tid + 192]));
}

// ====== layers 2/3 slim-tier (eid CSR, unpipelined — fallback only) ==========
__global__ __launch_bounds__(256) void gine64s_kernel(
    const int* __restrict__ rowptr, const int* __restrict__ eid_s,
    const int* __restrict__ src, const float* __restrict__ ea,
    const float* __restrict__ xin, const float* __restrict__ elw,
    const float* __restrict__ elb, const float* __restrict__ w1,
    const float* __restrict__ b1, const float* __restrict__ eps_p,
    float* __restrict__ tbuf, float* __restrict__ stats) {
  __shared__ float wl[64 * 64];
  __shared__ float hb[4][64];
  __shared__ float red[256];
  int tid = threadIdx.x, lane = tid & 63, wv = tid >> 6;
  for (int i = tid; i < 64 * 64; i += 256) wl[i] = w1[i];
  float wel[7];
#pragma unroll
  for (int k = 0; k < 7; k++) wel[k] = elw[k * 64 + lane];
  float bel = elb[lane], b1c = b1[lane];
  float ep = 1.0f + *eps_p;
  float s = 0.f, ss = 0.f;
  __syncthreads();
  int nw = gridDim.x * 4;
  for (int n = blockIdx.x * 4 + wv; n < NN; n += nw) {
    int r0 = rowptr[n], r1 = rowptr[n + 1];
    float acc = 0.f;
    for (int i = r0; i < r1; i++) {
      int e = eid_s[i];
      int sn = src[e];
      float m = bel;
#pragma unroll
      for (int k = 0; k < 7; k++) m = fmaf(ea[e * 7 + k], wel[k], m);
      m += xin[sn * 64 + lane];
      acc += fmaxf(m, 0.f);
    }
    float h = ep * xin[n * 64 + lane] + acc;
    hb[wv][lane] = h;
    float t = b1c;
#pragma unroll
    for (int k = 0; k < 64; k++) t = fmaf(hb[wv][k], wl[k * 64 + lane], t);
    tbuf[n * 64 + lane] = t;
    s += t;
    ss += t * t;
  }
  double* dsum = (double*)stats;
  red[tid] = s;
  __syncthreads();
  if (tid < 64) unsafeAtomicAdd(&dsum[tid], (double)(red[tid] + red[tid + 64] + red[tid + 128] + red[tid + 192]));
  __syncthreads();
  red[tid] = ss;
  __syncthreads();
  if (tid < 64) unsafeAtomicAdd(&dsum[64 + tid], (double)(red[tid] + red[tid + 64] + red[tid + 128] + red[tid + 192]));
}

// ===================== legacy (fallback tier B) kernels ======================
__global__ __launch_bounds__(256) void edge1_kernel(
    const float* __restrict__ x, const float* __restrict__ ea,
    const int* __restrict__ src, const int* __restrict__ dst,
    const float* __restrict__ elw, const float* __restrict__ elb,
    float* __restrict__ agg) {
  float w0[7], w1[7];
#pragma unroll
  for (int k = 0; k < 7; k++) { w0[k] = elw[k * 2]; w1[k] = elw[k * 2 + 1]; }
  float b0 = elb[0], b1 = elb[1];
  int stride = gridDim.x * 256;
  for (int e = blockIdx.x * 256 + threadIdx.x; e < NE; e += stride) {
    int s = src[e], d = dst[e];
    float m0 = b0, m1 = b1;
#pragma unroll
    for (int k = 0; k < 7; k++) {
      float a = ea[e * 7 + k];
      m0 = fmaf(a, w0[k], m0);
      m1 = fmaf(a, w1[k], m1);
    }
    m0 = fmaxf(m0 + x[s * 2 + 0], 0.f);
    m1 = fmaxf(m1 + x[s * 2 + 1], 0.f);
    unsafeAtomicAdd(&agg[d * 2 + 0], m0);
    unsafeAtomicAdd(&agg[d * 2 + 1], m1);
  }
}

__global__ __launch_bounds__(256) void edge64_kernel(
    const float* __restrict__ xin, const float* __restrict__ ea,
    const int* __restrict__ src, const int* __restrict__ dst,
    const float* __restrict__ elw, const float* __restrict__ elb,
    float* __restrict__ agg) {
  int lane = threadIdx.x & 63;
  int wid = (blockIdx.x * 256 + threadIdx.x) >> 6;
  int nw = (gridDim.x * 256) >> 6;
  float w[7];
#pragma unroll
  for (int k = 0; k < 7; k++) w[k] = elw[k * 64 + lane];
  float b = elb[lane];
  for (int e = wid; e < NE; e += nw) {
    int eu = __builtin_amdgcn_readfirstlane(e);
    int s = src[eu];
    int d = dst[eu];
    float m = b;
#pragma unroll
    for (int k = 0; k < 7; k++) m = fmaf(ea[eu * 7 + k], w[k], m);
    m += xin[s * 64 + lane];
    m = fmaxf(m, 0.f);
    unsafeAtomicAdd(&agg[d * 64 + lane], m);
  }
}

__global__ __launch_bounds__(256) void nodeA64_kernel(
    const float* __restrict__ xin, float* __restrict__ tbuf,
    const float* __restrict__ w1, const float* __restrict__ b1,
    const float* __restrict__ eps_p, float* __restrict__ stats) {
  __shared__ float wl[64 * 64];
  __shared__ float hbuf[4][64];
  __shared__ float red[256];
  int tid = threadIdx.x;
  int c = tid & 63, nl = tid >> 6;
  for (int i = tid; i < 64 * 64; i += 256) wl[i] = w1[i];
  float ep = 1.0f + *eps_p;
  float bc = b1[c];
  float s = 0.f, ss = 0.f;
  __syncthreads();
  for (int n0 = blockIdx.x * 4; n0 < NN; n0 += gridDim.x * 4) {
    int n = n0 + nl;
    bool valid = n < NN;
    float h = 0.f;
    if (valid) h = ep * xin[n * 64 + c] + tbuf[n * 64 + c];
    hbuf[nl][c] = h;
    __syncthreads();
    if (valid) {
      float t = bc;
#pragma unroll
      for (int k = 0; k < 64; k++) t = fmaf(hbuf[nl][k], wl[k * 64 + c], t);
      tbuf[n * 64 + c] = t;
      s += t;
      ss += t * t;
    }
    __syncthreads();
  }
  double* dsum = (double*)stats;
  red[tid] = s;
  __syncthreads();
  if (tid < 64) unsafeAtomicAdd(&dsum[tid], (double)(red[tid] + red[tid + 64] + red[tid + 128] + red[tid + 192]));
  __syncthreads();
  red[tid] = ss;
  __syncthreads();
  if (tid < 64) unsafeAtomicAdd(&dsum[64 + tid], (double)(red[tid] + red[tid + 64] + red[tid + 128] + red[tid + 192]));
}

// ===================== shared node kernels ===================================
__global__ __launch_bounds__(256) void nodeA2_kernel(
    const float* __restrict__ x, const float* __restrict__ agg1,
    float* __restrict__ tbuf, const float* __restrict__ w1,
    const float* __restrict__ b1, const float* __restrict__ eps_p,
    float* __restrict__ stats) {
  __shared__ float red[256];
  int tid = threadIdx.x;
  int c = tid & 63, nl = tid >> 6;
  float wa = w1[c], wb = w1[64 + c], bc = b1[c];
  float ep = 1.0f + *eps_p;
  float s = 0.f, ss = 0.f;
  for (int n0 = blockIdx.x * 4; n0 < NN; n0 += gridDim.x * 4) {
    int n = n0 + nl;
    if (n < NN) {
      float h0 = ep * x[n * 2 + 0] + agg1[n * 2 + 0];
      float h1 = ep * x[n * 2 + 1] + agg1[n * 2 + 1];
      float t = fmaf(h1, wb, fmaf(h0, wa, bc));
      tbuf[n * 64 + c] = t;
      s += t;
      ss += t * t;
    }
  }
  double* dsum = (double*)stats;
  red[tid] = s;
  __syncthreads();
  if (tid < 64) unsafeAtomicAdd(&dsum[tid], (double)(red[tid] + red[tid + 64] + red[tid + 128] + red[tid + 192]));
  __syncthreads();
  red[tid] = ss;
  __syncthreads();
  if (tid < 64) unsafeAtomicAdd(&dsum[64 + tid], (double)(red[tid] + red[tid + 64] + red[tid + 128] + red[tid + 192]));
}

// --- node B, barrier-free wave-per-node (same-wave LDS exchange, proven in
// --- gine64 kernels since R2): u=relu(BN(t)); out=relu(u@w2+b2); opt fp16 copy
__global__ __launch_bounds__(256) void nodeB_kernel(
    const float* __restrict__ tin, float* __restrict__ outb,
    const float* __restrict__ w2, const float* __restrict__ b2,
    const float* __restrict__ stats, const float* __restrict__ g,
    const float* __restrict__ bt, unsigned short* __restrict__ xh) {
  __shared__ float wl[64 * 64];
  __shared__ float ub[4][64];
  __shared__ float scsh[128];
  int tid = threadIdx.x;
  int lane = tid & 63, wv = tid >> 6;
  for (int i = tid; i < 64 * 64; i += 256) wl[i] = w2[i];
  if (tid < 64) {
    const double* ds = (const double*)stats;
    double m = ds[tid] / (double)NN;
    double v = ds[64 + tid] / (double)NN - m * m;
    float sc = g[tid] * (float)(1.0 / sqrt(v + 1e-5));
    scsh[tid] = sc;
    scsh[64 + tid] = bt[tid] - (float)m * sc;
  }
  float bc = b2[lane];
  __syncthreads();
  float scale = scsh[lane], shift = scsh[64 + lane];
  int nw = gridDim.x * 4;
  for (int n = blockIdx.x * 4 + wv; n < NN; n += nw) {
    float t = tin[n * 64 + lane];
    float u = fmaxf(fmaf(t, scale, shift), 0.f);
    ub[wv][lane] = u;  // same-wave LDS exchange (in-order DS pipe)
    float o = bc;
#pragma unroll
    for (int k = 0; k < 64; k++) o = fmaf(ub[wv][k], wl[k * 64 + lane], o);
    o = fmaxf(o, 0.f);
    outb[n * 64 + lane] = o;
    if (xh) xh[n * 64 + lane] = f1h(o);
  }
}

__global__ __launch_bounds__(256) void final_kernel(
    const float* __restrict__ xin, const float* __restrict__ regw,
    const float* __restrict__ regb, const float* __restrict__ endw,
    const float* __restrict__ endb, float* __restrict__ out) {
  __shared__ float wl[64 * 128];
  __shared__ float eb[256];
  int tid = threadIdx.x;
  int node = blockIdx.x * 256 + tid;
  bool valid = node < NN;
  float xr[64];
  if (valid) {
    const float4* xp = (const float4*)(xin + node * 64);
#pragma unroll
    for (int k4 = 0; k4 < 16; k4++) {
      float4 v = xp[k4];
      xr[k4 * 4 + 0] = v.x; xr[k4 * 4 + 1] = v.y;
      xr[k4 * 4 + 2] = v.z; xr[k4 * 4 + 3] = v.w;
    }
  }
  float y = 0.f;
  for (int ch = 0; ch < 4; ch++) {
    int j0 = ch * 125;
    __syncthreads();
    for (int idx = tid; idx < 64 * 125; idx += 256) {
      int k = idx / 125;
      int jl = idx - k * 125;
      wl[k * 128 + jl] = regw[k * 500 + j0 + jl];
    }
    if (tid < 125) { eb[tid] = regb[j0 + tid]; eb[128 + tid] = endw[j0 + tid]; }
    __syncthreads();
    if (valid) {
      int jl = 0;
      for (; jl + 4 <= 125; jl += 4) {
        float t0 = eb[jl], t1 = eb[jl + 1], t2 = eb[jl + 2], t3 = eb[jl + 3];
#pragma unroll
        for (int k = 0; k < 64; k++) {
          float4 w4 = *(const float4*)&wl[k * 128 + jl];
          float xv = xr[k];
          t0 = fmaf(xv, w4.x, t0);
          t1 = fmaf(xv, w4.y, t1);
          t2 = fmaf(xv, w4.z, t2);
          t3 = fmaf(xv, w4.w, t3);
        }
        t0 = t0 >= 0.f ? t0 : 0.01f * t0;
        t1 = t1 >= 0.f ? t1 : 0.01f * t1;
        t2 = t2 >= 0.f ? t2 : 0.01f * t2;
        t3 = t3 >= 0.f ? t3 : 0.01f * t3;
        y += t0 * eb[128 + jl] + t1 * eb[128 + jl + 1] + t2 * eb[128 + jl + 2] + t3 * eb[128 + jl + 3];
      }
      {
        float t = eb[124];
#pragma unroll
        for (int k = 0; k < 64; k++) t = fmaf(xr[k], wl[k * 128 + 124], t);
        t = t >= 0.f ? t : 0.01f * t;
        y += t * eb[128 + 124];
      }
    }
  }
  if (valid) out[node] = y + endb[0];
}

extern "C" void kernel_launch(void* const* d_in, const int* in_sizes, int n_in,
                              void* d_out, int out_size, void* d_ws, size_t ws_size,
                              hipStream_t stream) {
  const float* x    = (const float*)d_in[0];
  const float* ea   = (const float*)d_in[1];
  const int*   ei   = (const int*)d_in[2];
  const float* eps1 = (const float*)d_in[4];
  const float* el1w = (const float*)d_in[5];
  const float* el1b = (const float*)d_in[6];
  const float* n1w1 = (const float*)d_in[7];
  const float* n1b1 = (const float*)d_in[8];
  const float* n1g  = (const float*)d_in[9];
  const float* n1bt = (const float*)d_in[10];
  const float* n1w2 = (const float*)d_in[11];
  const float* n1b2 = (const float*)d_in[12];
  const float* eps2 = (const float*)d_in[13];
  const float* el2w = (const float*)d_in[14];
  const float* el2b = (const float*)d_in[15];
  const float* n2w1 = (const float*)d_in[16];
  const float* n2b1 = (const float*)d_in[17];
  const float* n2g  = (const float*)d_in[18];
  const float* n2bt = (const float*)d_in[19];
  const float* n2w2 = (const float*)d_in[20];
  const float* n2b2 = (const float*)d_in[21];
  const float* regw = (const float*)d_in[22];
  const float* regb = (const float*)d_in[23];
  const float* endw = (const float*)d_in[24];
  const float* endb = (const float*)d_in[25];
  const int* srcp = ei;
  const int* dstp = ei + NE;

  // ---- tier-A layout (float offsets) ----
  const size_t o_stats  = 0;          // 768 floats = 3 layers × 128 doubles
  const size_t o_cnt    = 768;        // NN ints (contiguous w/ stats: one memset)
  const size_t o_rowptr = 100768;     // NN+1 ints
  const size_t o_buf0   = 200832;     // N*64 floats; msg1 [E]float2 pre-layer-2
  const size_t o_buf1   = 6600832;    // N*64 floats
  const size_t o_xh     = 13000832;   // N*64 fp16 (= 3.2M floats)
  const size_t o_agg1   = 16200832;   // N*2 floats
  const size_t o_edat   = 16400832;   // packed: E uint4 | slim: E ints
  const size_t needA2 = (o_edat + (size_t)NE * 4) * 4;  // ~116.8 MB
  const size_t needA1 = (o_edat + (size_t)NE) * 4;      // ~78.4 MB
  const size_t needB  = (2 * 6600000 + 384) * 4;        // ~52.8 MB

  float* wsf = (float*)d_ws;

  if (ws_size >= needA1) {
    const bool packed = ws_size >= needA2;
    float* stats0 = wsf + o_stats;        // layer 1
    float* stats1 = wsf + o_stats + 256;  // layer 2
    float* stats2 = wsf + o_stats + 512;  // layer 3
    int* cnt     = (int*)(wsf + o_cnt);
    int* rowptr  = (int*)(wsf + o_rowptr);
    float* buf0  = wsf + o_buf0;
    float* buf1  = wsf + o_buf1;
    unsigned short* xh = (unsigned short*)(wsf + o_xh);
    float* agg1  = wsf + o_agg1;
    uint4* erec  = (uint4*)(wsf + o_edat);
    float* msg1  = buf0;  // [E]float2 == N*64 floats exactly; free until layer 2

    // ---- one memset covers stats(3 layers) + cnt ----
    hipMemsetAsync(wsf, 0, (768 + NN) * sizeof(float), stream);

    // ---- CSR build (once, shared by all 3 layers) ----
    count_kernel<<<4096, 256, 0, stream>>>(dstp, cnt);
    scan_kernel<<<1, 1024, 0, stream>>>(cnt, rowptr, cnt);
    if (packed)
      scatter2e_kernel<<<4096, 256, 0, stream>>>(srcp, dstp, ea, cnt, erec,
                                                 x, el1w, el1b, msg1);
    else
      scatter1_kernel<<<4096, 256, 0, stream>>>(dstp, cnt, (int*)(wsf + o_edat));

    // ---- layer 1 ----
    if (packed)
      l1sum_kernel<<<391, 256, 0, stream>>>(rowptr, msg1, agg1);
    else
      l1agg_kernel<<<391, 256, 0, stream>>>(rowptr, (const int*)(wsf + o_edat),
                                            srcp, ea, x, el1w, el1b, agg1);
    nodeA2_kernel<<<2048, 256, 0, stream>>>(x, agg1, buf1, n1w1, n1b1, eps1, stats0);
    nodeB_kernel<<<2048, 256, 0, stream>>>(buf1, buf1, n1w2, n1b2, stats0,
                                           n1g, n1bt, packed ? xh : nullptr);

    // ---- layers 2,3 (shared weights) ----
    if (packed) {
      gine64h_kernel<<<4096, 256, 0, stream>>>(rowptr, erec, buf1, xh,
                                               el2w, el2b, n2w1, n2b1, eps2,
                                               buf0, stats1);
      nodeB_kernel<<<2048, 256, 0, stream>>>(buf0, buf0, n2w2, n2b2, stats1,
                                             n2g, n2bt, xh);
      gine64h_kernel<<<4096, 256, 0, stream>>>(rowptr, erec, buf0, xh,
                                               el2w, el2b, n2w1, n2b1, eps2,
                                               buf1, stats2);
      nodeB_kernel<<<2048, 256, 0, stream>>>(buf1, buf1, n2w2, n2b2, stats2,
                                             n2g, n2bt, nullptr);
      final_kernel<<<(NN + 255) / 256, 256, 0, stream>>>(buf1, regw, regb, endw,
                                                         endb, (float*)d_out);
    } else {
      float* cur = buf1;
      float* wrk = buf0;
      float* sl[2] = {stats1, stats2};
      for (int l = 0; l < 2; l++) {
        gine64s_kernel<<<4096, 256, 0, stream>>>(rowptr, (const int*)(wsf + o_edat),
                                                 srcp, ea, cur, el2w, el2b, n2w1,
                                                 n2b1, eps2, wrk, sl[l]);
        nodeB_kernel<<<2048, 256, 0, stream>>>(wrk, wrk, n2w2, n2b2, sl[l],
                                               n2g, n2bt, nullptr);
        float* tmp = cur; cur = wrk; wrk = tmp;
      }
      final_kernel<<<(NN + 255) / 256, 256, 0, stream>>>(cur, regw, regb, endw,
                                                         endb, (float*)d_out);
    }
    return;
  }

  // ================= fallback tier B (round-1 proven path) =================
  if (ws_size < needB) return;
  const size_t BUF = 6600000;
  float* buf0 = (float*)d_ws;
  float* buf1 = buf0 + BUF;
  float* stats = buf1 + BUF;

  float* t1 = buf1;
  float* agg1 = buf1 + NN * 64;
  hipMemsetAsync(agg1, 0, NN * 2 * sizeof(float), stream);
  hipMemsetAsync(stats, 0, 128 * sizeof(double), stream);
  edge1_kernel<<<2048, 256, 0, stream>>>(x, ea, srcp, dstp, el1w, el1b, agg1);
  nodeA2_kernel<<<2048, 256, 0, stream>>>(x, agg1, t1, n1w1, n1b1, eps1, stats);
  nodeB_kernel<<<2048, 256, 0, stream>>>(t1, buf1, n1w2, n1b2, stats, n1g, n1bt,
                                         nullptr);

  float* cur = buf1;
  float* wrk = buf0;
  for (int l = 0; l < 2; l++) {
    hipMemsetAsync(wrk, 0, NN * 64 * sizeof(float), stream);
    hipMemsetAsync(stats, 0, 128 * sizeof(double), stream);
    edge64_kernel<<<2048, 256, 0, stream>>>(cur, ea, srcp, dstp, el2w, el2b, wrk);
    nodeA64_kernel<<<2048, 256, 0, stream>>>(cur, wrk, n2w1, n2b1, eps2, stats);
    nodeB_kernel<<<2048, 256, 0, stream>>>(wrk, wrk, n2w2, n2b2, stats, n2g, n2bt,
                                           nullptr);
    float* tmp = cur; cur = wrk; wrk = tmp;
  }

  final_kernel<<<(NN + 255) / 256, 256, 0, stream>>>(cur, regw, regb, endw, endb,
                                                     (float*)d_out);
}

// Round 15
// 1276.145 us; speedup vs baseline: 1.0717x; 1.0303x over previous
//
#include <hip/hip_runtime.h>
#include <hip/hip_fp16.h>

#define NN 100000
#define NE 3200000

// ---------- fp16 pack/unpack helpers ----------
__device__ inline unsigned pkh(float a, float b) {
  __half2 h;
  h.x = __float2half(a);
  h.y = __float2half(b);
  unsigned u;
  __builtin_memcpy(&u, &h, 4);
  return u;
}
__device__ inline float2 uph(unsigned u) {
  __half2 h;
  __builtin_memcpy(&h, &u, 4);
  return __half22float2(h);
}
__device__ inline float h1f(unsigned short v) {
  __half h;
  __builtin_memcpy(&h, &v, 2);
  return __half2float(h);
}
__device__ inline unsigned short f1h(float f) {
  __half h = __float2half(f);
  unsigned short u;
  __builtin_memcpy(&u, &h, 2);
  return u;
}

// ===================== CSR build =====================
__global__ __launch_bounds__(256) void count_kernel(const int* __restrict__ dst,
                                                    int* __restrict__ cnt) {
  int stride = gridDim.x * 256;
  for (int e = blockIdx.x * 256 + threadIdx.x; e < NE; e += stride)
    atomicAdd(&cnt[dst[e]], 1);
}

// single-block exclusive scan over NN counts -> rowptr[0..NN]; ofs=running copy
__global__ __launch_bounds__(1024) void scan_kernel(const int* __restrict__ cnt,
                                                    int* __restrict__ rowptr,
                                                    int* __restrict__ ofs) {
  __shared__ int bsum[1024];
  int tid = threadIdx.x;
  const int CH = (NN + 1023) / 1024;
  int lo = tid * CH, hi = lo + CH < NN ? lo + CH : NN;
  if (lo > NN) lo = NN;
  if (hi < lo) hi = lo;
  int s = 0;
  for (int i = lo; i < hi; i++) s += cnt[i];
  bsum[tid] = s;
  __syncthreads();
  for (int off = 1; off < 1024; off <<= 1) {
    int v = bsum[tid];
    int u = (tid >= off) ? bsum[tid - off] : 0;
    __syncthreads();
    bsum[tid] = v + u;
    __syncthreads();
  }
  int pre = (tid == 0) ? 0 : bsum[tid - 1];
  for (int i = lo; i < hi; i++) {
    int cv = cnt[i];
    rowptr[i] = pre;
    ofs[i] = pre;
    pre += cv;
  }
  if (tid == 1023) rowptr[NN] = pre;
}

// packed scatter, single 16B record (src embedded via stolen ea6 mantissa bit)
// + fused layer-1 message stream:
//   erec[pos] = uint4{ pkh(ea0,ea1), pkh(ea2,ea3), pkh(ea4,ea5),
//                      (f1h(ea6)&0xFFFE) | (src>>16) | ((src&0xFFFF)<<16) }
//   msg1[pos] = relu(x[src,:2] + ea@el1w + el1b) as float2   (fp32 inputs)
__global__ __launch_bounds__(256) void scatter2e_kernel(
    const int* __restrict__ src, const int* __restrict__ dst,
    const float* __restrict__ ea, int* __restrict__ ofs,
    uint4* __restrict__ erec, const float* __restrict__ x,
    const float* __restrict__ elw, const float* __restrict__ elb,
    float* __restrict__ msg1) {
  float w0[7], w1r[7];
#pragma unroll
  for (int k = 0; k < 7; k++) { w0[k] = elw[k * 2]; w1r[k] = elw[k * 2 + 1]; }
  float b0 = elb[0], b1 = elb[1];
  int stride = gridDim.x * 256;
  for (int e = blockIdx.x * 256 + threadIdx.x; e < NE; e += stride) {
    int sn = src[e];
    int pos = atomicAdd(&ofs[dst[e]], 1);
    float av[7];
#pragma unroll
    for (int k = 0; k < 7; k++) av[k] = ea[e * 7 + k];
    uint4 r;
    r.x = pkh(av[0], av[1]);
    r.y = pkh(av[2], av[3]);
    r.z = pkh(av[4], av[5]);
    r.w = ((unsigned)f1h(av[6]) & 0xFFFEu) | ((unsigned)sn >> 16) |
          (((unsigned)sn & 0xFFFFu) << 16);
    erec[pos] = r;
    float m0 = b0, m1 = b1;
#pragma unroll
    for (int k = 0; k < 7; k++) {
      m0 = fmaf(av[k], w0[k], m0);
      m1 = fmaf(av[k], w1r[k], m1);
    }
    m0 = fmaxf(m0 + x[sn * 2 + 0], 0.f);
    m1 = fmaxf(m1 + x[sn * 2 + 1], 0.f);
    float2 mv; mv.x = m0; mv.y = m1;
    ((float2*)msg1)[pos] = mv;
  }
}

// slim scatter: sorted edge ids only
__global__ __launch_bounds__(256) void scatter1_kernel(
    const int* __restrict__ dst, int* __restrict__ ofs, int* __restrict__ eid_s) {
  int stride = gridDim.x * 256;
  for (int e = blockIdx.x * 256 + threadIdx.x; e < NE; e += stride) {
    int pos = atomicAdd(&ofs[dst[e]], 1);
    eid_s[pos] = e;
  }
}

// == layer 1 fused (packed tier): wave-per-node segment-sum of msg1 + h +
// == w1[2,64] matmul + BN stats. Barrier-free (butterfly shuffle reduce). ====
__global__ __launch_bounds__(256) void l1node_kernel(
    const int* __restrict__ rowptr, const float* __restrict__ msg1,
    const float* __restrict__ x, const float* __restrict__ w1,
    const float* __restrict__ b1, const float* __restrict__ eps_p,
    float* __restrict__ tbuf, float* __restrict__ stats) {
  __shared__ float red[256];
  int tid = threadIdx.x, lane = tid & 63, wv = tid >> 6;
  float wa = w1[lane], wb = w1[64 + lane], bc = b1[lane];
  float ep = 1.0f + *eps_p;
  float s = 0.f, ss = 0.f;
  const float2* mp = (const float2*)msg1;
  int nw = gridDim.x * 4;
  for (int n = blockIdx.x * 4 + wv; n < NN; n += nw) {
    int r0 = rowptr[n], r1 = rowptr[n + 1];
    float a0 = 0.f, a1 = 0.f;
    for (int i = r0 + lane; i < r1; i += 64) {
      float2 v = mp[i];
      a0 += v.x;
      a1 += v.y;
    }
#pragma unroll
    for (int off = 32; off >= 1; off >>= 1) {
      a0 += __shfl_xor(a0, off, 64);
      a1 += __shfl_xor(a1, off, 64);
    }
    float h0 = ep * x[n * 2 + 0] + a0;
    float h1 = ep * x[n * 2 + 1] + a1;
    float t = fmaf(h1, wb, fmaf(h0, wa, bc));
    tbuf[n * 64 + lane] = t;
    s += t;
    ss += t * t;
  }
  double* dsum = (double*)stats;
  red[tid] = s;
  __syncthreads();
  if (tid < 64) unsafeAtomicAdd(&dsum[tid], (double)(red[tid] + red[tid + 64] + red[tid + 128] + red[tid + 192]));
  __syncthreads();
  red[tid] = ss;
  __syncthreads();
  if (tid < 64) unsafeAtomicAdd(&dsum[64 + tid], (double)(red[tid] + red[tid + 64] + red[tid + 128] + red[tid + 192]));
}

// =========== layer 1 slim-tier aggregate (thread per node, eid CSR) ==========
__global__ __launch_bounds__(256) void l1agg_kernel(
    const int* __restrict__ rowptr, const int* __restrict__ eid_s,
    const int* __restrict__ src, const float* __restrict__ ea,
    const float* __restrict__ x, const float* __restrict__ elw,
    const float* __restrict__ elb, float* __restrict__ agg) {
  float w0[7], w1r[7];
#pragma unroll
  for (int k = 0; k < 7; k++) { w0[k] = elw[k * 2]; w1r[k] = elw[k * 2 + 1]; }
  float b0 = elb[0], b1 = elb[1];
  int stride = gridDim.x * 256;
  for (int n = blockIdx.x * 256 + threadIdx.x; n < NN; n += stride) {
    int r0 = rowptr[n], r1 = rowptr[n + 1];
    float a0 = 0.f, a1 = 0.f;
    for (int i = r0; i < r1; i++) {
      int e = eid_s[i];
      int sn = src[e];
      float m0 = b0, m1 = b1;
#pragma unroll
      for (int k = 0; k < 7; k++) {
        float a = ea[e * 7 + k];
        m0 = fmaf(a, w0[k], m0);
        m1 = fmaf(a, w1r[k], m1);
      }
      m0 = fmaxf(m0 + x[sn * 2 + 0], 0.f);
      m1 = fmaxf(m1 + x[sn * 2 + 1], 0.f);
      a0 += m0; a1 += m1;
    }
    agg[n * 2 + 0] = a0;
    agg[n * 2 + 1] = a1;
  }
}

// =========== layer 1 slim-tier node A (cross-wave, fallback only) ============
__global__ __launch_bounds__(256) void nodeA2_kernel(
    const float* __restrict__ x, const float* __restrict__ agg1,
    float* __restrict__ tbuf, const float* __restrict__ w1,
    const float* __restrict__ b1, const float* __restrict__ eps_p,
    float* __restrict__ stats) {
  __shared__ float red[256];
  int tid = threadIdx.x;
  int c = tid & 63, nl = tid >> 6;
  float wa = w1[c], wb = w1[64 + c], bc = b1[c];
  float ep = 1.0f + *eps_p;
  float s = 0.f, ss = 0.f;
  for (int n0 = blockIdx.x * 4; n0 < NN; n0 += gridDim.x * 4) {
    int n = n0 + nl;
    if (n < NN) {
      float h0 = ep * x[n * 2 + 0] + agg1[n * 2 + 0];
      float h1 = ep * x[n * 2 + 1] + agg1[n * 2 + 1];
      float t = fmaf(h1, wb, fmaf(h0, wa, bc));
      tbuf[n * 64 + c] = t;
      s += t;
      ss += t * t;
    }
  }
  double* dsum = (double*)stats;
  red[tid] = s;
  __syncthreads();
  if (tid < 64) unsafeAtomicAdd(&dsum[tid], (double)(red[tid] + red[tid + 64] + red[tid + 128] + red[tid + 192]));
  __syncthreads();
  red[tid] = ss;
  __syncthreads();
  if (tid < 64) unsafeAtomicAdd(&dsum[64 + tid], (double)(red[tid] + red[tid + 64] + red[tid + 128] + red[tid + 192]));
}

#define PROJH2(m, u) do { \
  float2 q0 = uph((u).x), q1 = uph((u).y), q2 = uph((u).z); \
  float e6 = h1f((unsigned short)((u).w & 0xFFFEu)); \
  m = bel; \
  m = fmaf(q0.x, wel[0], m); m = fmaf(q0.y, wel[1], m); \
  m = fmaf(q1.x, wel[2], m); m = fmaf(q1.y, wel[3], m); \
  m = fmaf(q2.x, wel[4], m); m = fmaf(q2.y, wel[5], m); \
  m = fmaf(e6, wel[6], m); } while (0)

#define SRCOF(u) ((int)((((u).w & 1u) << 16) | ((u).w >> 16)))

// ====== layers 2/3 fused, 16B records w/ embedded src, 4-deep pipeline =======
__global__ __launch_bounds__(256) void gine64h_kernel(
    const int* __restrict__ rowptr, const uint4* __restrict__ erec,
    const float* __restrict__ xin, const unsigned short* __restrict__ xh,
    const float* __restrict__ elw, const float* __restrict__ elb,
    const float* __restrict__ w1, const float* __restrict__ b1,
    const float* __restrict__ eps_p, float* __restrict__ tbuf,
    float* __restrict__ stats) {
  __shared__ float wl[64 * 64];
  __shared__ float hb[4][64];
  __shared__ float red[256];
  int tid = threadIdx.x, lane = tid & 63, wv = tid >> 6;
  for (int i2 = tid; i2 < 64 * 64; i2 += 256) wl[i2] = w1[i2];
  float wel[7];
#pragma unroll
  for (int k = 0; k < 7; k++) wel[k] = elw[k * 64 + lane];
  float bel = elb[lane], b1c = b1[lane];
  float ep = 1.0f + *eps_p;
  float s = 0.f, ss = 0.f;
  __syncthreads();
  const unsigned short* xl = xh + lane;
  int nw = gridDim.x * 4;
  for (int n = blockIdx.x * 4 + wv; n < NN; n += nw) {
    int r0 = rowptr[n], r1 = rowptr[n + 1];
    float acc = 0.f;
    int i = r0;
    int rem = r1 - r0;
    if (rem >= 4) {
      uint4 u0 = erec[i], u1 = erec[i + 1], u2 = erec[i + 2], u3 = erec[i + 3];
      while (true) {
        // decode srcs (2 VALU each) and issue 4 independent gathers
        int s0 = SRCOF(u0), s1 = SRCOF(u1), s2 = SRCOF(u2), s3 = SRCOF(u3);
        float g0 = h1f(xl[s0 * 64]);
        float g1 = h1f(xl[s1 * 64]);
        float g2 = h1f(xl[s2 * 64]);
        float g3 = h1f(xl[s3 * 64]);
        i += 4; rem -= 4;
        bool more = rem >= 4;
        int ip = more ? i : r0;  // dummy (valid) address when finishing
        // prefetch next group's records while gathers are in flight
        uint4 v0 = erec[ip], v1 = erec[ip + 1], v2 = erec[ip + 2], v3 = erec[ip + 3];
        // edge projections (independent of gathers)
        float m0, m1, m2, m3;
        PROJH2(m0, u0); PROJH2(m1, u1); PROJH2(m2, u2); PROJH2(m3, u3);
        acc += fmaxf(m0 + g0, 0.f);
        acc += fmaxf(m1 + g1, 0.f);
        acc += fmaxf(m2 + g2, 0.f);
        acc += fmaxf(m3 + g3, 0.f);
        u0 = v0; u1 = v1; u2 = v2; u3 = v3;
        if (!more) break;
      }
    }
    for (; i < r1; i++) {  // tail (0..3 edges)
      uint4 u = erec[i];
      int sn = SRCOF(u);
      float m;
      PROJH2(m, u);
      m += h1f(xl[sn * 64]);
      acc += fmaxf(m, 0.f);
    }
    float h = ep * xin[n * 64 + lane] + acc;
    hb[wv][lane] = h;  // same-wave LDS exchange (in-order DS pipe)
    float t = b1c;
#pragma unroll
    for (int k = 0; k < 64; k++) t = fmaf(hb[wv][k], wl[k * 64 + lane], t);
    tbuf[n * 64 + lane] = t;
    s += t;
    ss += t * t;
  }
  double* dsum = (double*)stats;
  red[tid] = s;
  __syncthreads();
  if (tid < 64) unsafeAtomicAdd(&dsum[tid], (double)(red[tid] + red[tid + 64] + red[tid + 128] + red[tid + 192]));
  __syncthreads();
  red[tid] = ss;
  __syncthreads();
  if (tid < 64) unsafeAtomicAdd(&dsum[64 + tid], (double)(red[tid] + red[tid + 64] + red[tid + 128] + red[tid + 192]));
}

// ====== layers 2/3 slim-tier (eid CSR, unpipelined — fallback only) ==========
__global__ __launch_bounds__(256) void gine64s_kernel(
    const int* __restrict__ rowptr, const int* __restrict__ eid_s,
    const int* __restrict__ src, const float* __restrict__ ea,
    const float* __restrict__ xin, const float* __restrict__ elw,
    const float* __restrict__ elb, const float* __restrict__ w1,
    const float* __restrict__ b1, const float* __restrict__ eps_p,
    float* __restrict__ tbuf, float* __restrict__ stats) {
  __shared__ float wl[64 * 64];
  __shared__ float hb[4][64];
  __shared__ float red[256];
  int tid = threadIdx.x, lane = tid & 63, wv = tid >> 6;
  for (int i = tid; i < 64 * 64; i += 256) wl[i] = w1[i];
  float wel[7];
#pragma unroll
  for (int k = 0; k < 7; k++) wel[k] = elw[k * 64 + lane];
  float bel = elb[lane], b1c = b1[lane];
  float ep = 1.0f + *eps_p;
  float s = 0.f, ss = 0.f;
  __syncthreads();
  int nw = gridDim.x * 4;
  for (int n = blockIdx.x * 4 + wv; n < NN; n += nw) {
    int r0 = rowptr[n], r1 = rowptr[n + 1];
    float acc = 0.f;
    for (int i = r0; i < r1; i++) {
      int e = eid_s[i];
      int sn = src[e];
      float m = bel;
#pragma unroll
      for (int k = 0; k < 7; k++) m = fmaf(ea[e * 7 + k], wel[k], m);
      m += xin[sn * 64 + lane];
      acc += fmaxf(m, 0.f);
    }
    float h = ep * xin[n * 64 + lane] + acc;
    hb[wv][lane] = h;
    float t = b1c;
#pragma unroll
    for (int k = 0; k < 64; k++) t = fmaf(hb[wv][k], wl[k * 64 + lane], t);
    tbuf[n * 64 + lane] = t;
    s += t;
    ss += t * t;
  }
  double* dsum = (double*)stats;
  red[tid] = s;
  __syncthreads();
  if (tid < 64) unsafeAtomicAdd(&dsum[tid], (double)(red[tid] + red[tid + 64] + red[tid + 128] + red[tid + 192]));
  __syncthreads();
  red[tid] = ss;
  __syncthreads();
  if (tid < 64) unsafeAtomicAdd(&dsum[64 + tid], (double)(red[tid] + red[tid + 64] + red[tid + 128] + red[tid + 192]));
}

// ===================== legacy (fallback tier B) kernels ======================
__global__ __launch_bounds__(256) void edge1_kernel(
    const float* __restrict__ x, const float* __restrict__ ea,
    const int* __restrict__ src, const int* __restrict__ dst,
    const float* __restrict__ elw, const float* __restrict__ elb,
    float* __restrict__ agg) {
  float w0[7], w1[7];
#pragma unroll
  for (int k = 0; k < 7; k++) { w0[k] = elw[k * 2]; w1[k] = elw[k * 2 + 1]; }
  float b0 = elb[0], b1 = elb[1];
  int stride = gridDim.x * 256;
  for (int e = blockIdx.x * 256 + threadIdx.x; e < NE; e += stride) {
    int s = src[e], d = dst[e];
    float m0 = b0, m1 = b1;
#pragma unroll
    for (int k = 0; k < 7; k++) {
      float a = ea[e * 7 + k];
      m0 = fmaf(a, w0[k], m0);
      m1 = fmaf(a, w1[k], m1);
    }
    m0 = fmaxf(m0 + x[s * 2 + 0], 0.f);
    m1 = fmaxf(m1 + x[s * 2 + 1], 0.f);
    unsafeAtomicAdd(&agg[d * 2 + 0], m0);
    unsafeAtomicAdd(&agg[d * 2 + 1], m1);
  }
}

__global__ __launch_bounds__(256) void edge64_kernel(
    const float* __restrict__ xin, const float* __restrict__ ea,
    const int* __restrict__ src, const int* __restrict__ dst,
    const float* __restrict__ elw, const float* __restrict__ elb,
    float* __restrict__ agg) {
  int lane = threadIdx.x & 63;
  int wid = (blockIdx.x * 256 + threadIdx.x) >> 6;
  int nw = (gridDim.x * 256) >> 6;
  float w[7];
#pragma unroll
  for (int k = 0; k < 7; k++) w[k] = elw[k * 64 + lane];
  float b = elb[lane];
  for (int e = wid; e < NE; e += nw) {
    int eu = __builtin_amdgcn_readfirstlane(e);
    int s = src[eu];
    int d = dst[eu];
    float m = b;
#pragma unroll
    for (int k = 0; k < 7; k++) m = fmaf(ea[eu * 7 + k], w[k], m);
    m += xin[s * 64 + lane];
    m = fmaxf(m, 0.f);
    unsafeAtomicAdd(&agg[d * 64 + lane], m);
  }
}

__global__ __launch_bounds__(256) void nodeA64_kernel(
    const float* __restrict__ xin, float* __restrict__ tbuf,
    const float* __restrict__ w1, const float* __restrict__ b1,
    const float* __restrict__ eps_p, float* __restrict__ stats) {
  __shared__ float wl[64 * 64];
  __shared__ float hbuf[4][64];
  __shared__ float red[256];
  int tid = threadIdx.x;
  int c = tid & 63, nl = tid >> 6;
  for (int i = tid; i < 64 * 64; i += 256) wl[i] = w1[i];
  float ep = 1.0f + *eps_p;
  float bc = b1[c];
  float s = 0.f, ss = 0.f;
  __syncthreads();
  for (int n0 = blockIdx.x * 4; n0 < NN; n0 += gridDim.x * 4) {
    int n = n0 + nl;
    bool valid = n < NN;
    float h = 0.f;
    if (valid) h = ep * xin[n * 64 + c] + tbuf[n * 64 + c];
    hbuf[nl][c] = h;
    __syncthreads();
    if (valid) {
      float t = bc;
#pragma unroll
      for (int k = 0; k < 64; k++) t = fmaf(hbuf[nl][k], wl[k * 64 + c], t);
      tbuf[n * 64 + c] = t;
      s += t;
      ss += t * t;
    }
    __syncthreads();
  }
  double* dsum = (double*)stats;
  red[tid] = s;
  __syncthreads();
  if (tid < 64) unsafeAtomicAdd(&dsum[tid], (double)(red[tid] + red[tid + 64] + red[tid + 128] + red[tid + 192]));
  __syncthreads();
  red[tid] = ss;
  __syncthreads();
  if (tid < 64) unsafeAtomicAdd(&dsum[64 + tid], (double)(red[tid] + red[tid + 64] + red[tid + 128] + red[tid + 192]));
}

// --- node B, barrier-free wave-per-node (same-wave LDS exchange):
// --- u=relu(BN(t)); out=relu(u@w2+b2); optional fp16 copy
__global__ __launch_bounds__(256) void nodeB_kernel(
    const float* __restrict__ tin, float* __restrict__ outb,
    const float* __restrict__ w2, const float* __restrict__ b2,
    const float* __restrict__ stats, const float* __restrict__ g,
    const float* __restrict__ bt, unsigned short* __restrict__ xh) {
  __shared__ float wl[64 * 64];
  __shared__ float ub[4][64];
  __shared__ float scsh[128];
  int tid = threadIdx.x;
  int lane = tid & 63, wv = tid >> 6;
  for (int i = tid; i < 64 * 64; i += 256) wl[i] = w2[i];
  if (tid < 64) {
    const double* ds = (const double*)stats;
    double m = ds[tid] / (double)NN;
    double v = ds[64 + tid] / (double)NN - m * m;
    float sc = g[tid] * (float)(1.0 / sqrt(v + 1e-5));
    scsh[tid] = sc;
    scsh[64 + tid] = bt[tid] - (float)m * sc;
  }
  float bc = b2[lane];
  __syncthreads();
  float scale = scsh[lane], shift = scsh[64 + lane];
  int nw = gridDim.x * 4;
  for (int n = blockIdx.x * 4 + wv; n < NN; n += nw) {
    float t = tin[n * 64 + lane];
    float u = fmaxf(fmaf(t, scale, shift), 0.f);
    ub[wv][lane] = u;  // same-wave LDS exchange (in-order DS pipe)
    float o = bc;
#pragma unroll
    for (int k = 0; k < 64; k++) o = fmaf(ub[wv][k], wl[k * 64 + lane], o);
    o = fmaxf(o, 0.f);
    outb[n * 64 + lane] = o;
    if (xh) xh[n * 64 + lane] = f1h(o);
  }
}

__global__ __launch_bounds__(256) void final_kernel(
    const float* __restrict__ xin, const float* __restrict__ regw,
    const float* __restrict__ regb, const float* __restrict__ endw,
    const float* __restrict__ endb, float* __restrict__ out) {
  __shared__ float wl[64 * 128];
  __shared__ float eb[256];
  int tid = threadIdx.x;
  int node = blockIdx.x * 256 + tid;
  bool valid = node < NN;
  float xr[64];
  if (valid) {
    const float4* xp = (const float4*)(xin + node * 64);
#pragma unroll
    for (int k4 = 0; k4 < 16; k4++) {
      float4 v = xp[k4];
      xr[k4 * 4 + 0] = v.x; xr[k4 * 4 + 1] = v.y;
      xr[k4 * 4 + 2] = v.z; xr[k4 * 4 + 3] = v.w;
    }
  }
  float y = 0.f;
  for (int ch = 0; ch < 4; ch++) {
    int j0 = ch * 125;
    __syncthreads();
    for (int idx = tid; idx < 64 * 125; idx += 256) {
      int k = idx / 125;
      int jl = idx - k * 125;
      wl[k * 128 + jl] = regw[k * 500 + j0 + jl];
    }
    if (tid < 125) { eb[tid] = regb[j0 + tid]; eb[128 + tid] = endw[j0 + tid]; }
    __syncthreads();
    if (valid) {
      int jl = 0;
      for (; jl + 4 <= 125; jl += 4) {
        float t0 = eb[jl], t1 = eb[jl + 1], t2 = eb[jl + 2], t3 = eb[jl + 3];
#pragma unroll
        for (int k = 0; k < 64; k++) {
          float4 w4 = *(const float4*)&wl[k * 128 + jl];
          float xv = xr[k];
          t0 = fmaf(xv, w4.x, t0);
          t1 = fmaf(xv, w4.y, t1);
          t2 = fmaf(xv, w4.z, t2);
          t3 = fmaf(xv, w4.w, t3);
        }
        t0 = t0 >= 0.f ? t0 : 0.01f * t0;
        t1 = t1 >= 0.f ? t1 : 0.01f * t1;
        t2 = t2 >= 0.f ? t2 : 0.01f * t2;
        t3 = t3 >= 0.f ? t3 : 0.01f * t3;
        y += t0 * eb[128 + jl] + t1 * eb[128 + jl + 1] + t2 * eb[128 + jl + 2] + t3 * eb[128 + jl + 3];
      }
      {
        float t = eb[124];
#pragma unroll
        for (int k = 0; k < 64; k++) t = fmaf(xr[k], wl[k * 128 + 124], t);
        t = t >= 0.f ? t : 0.01f * t;
        y += t * eb[128 + 124];
      }
    }
  }
  if (valid) out[node] = y + endb[0];
}

extern "C" void kernel_launch(void* const* d_in, const int* in_sizes, int n_in,
                              void* d_out, int out_size, void* d_ws, size_t ws_size,
                              hipStream_t stream) {
  const float* x    = (const float*)d_in[0];
  const float* ea   = (const float*)d_in[1];
  const int*   ei   = (const int*)d_in[2];
  const float* eps1 = (const float*)d_in[4];
  const float* el1w = (const float*)d_in[5];
  const float* el1b = (const float*)d_in[6];
  const float* n1w1 = (const float*)d_in[7];
  const float* n1b1 = (const float*)d_in[8];
  const float* n1g  = (const float*)d_in[9];
  const float* n1bt = (const float*)d_in[10];
  const float* n1w2 = (const float*)d_in[11];
  const float* n1b2 = (const float*)d_in[12];
  const float* eps2 = (const float*)d_in[13];
  const float* el2w = (const float*)d_in[14];
  const float* el2b = (const float*)d_in[15];
  const float* n2w1 = (const float*)d_in[16];
  const float* n2b1 = (const float*)d_in[17];
  const float* n2g  = (const float*)d_in[18];
  const float* n2bt = (const float*)d_in[19];
  const float* n2w2 = (const float*)d_in[20];
  const float* n2b2 = (const float*)d_in[21];
  const float* regw = (const float*)d_in[22];
  const float* regb = (const float*)d_in[23];
  const float* endw = (const float*)d_in[24];
  const float* endb = (const float*)d_in[25];
  const int* srcp = ei;
  const int* dstp = ei + NE;

  // ---- tier-A layout (float offsets) ----
  const size_t o_stats  = 0;          // 768 floats = 3 layers × 128 doubles
  const size_t o_cnt    = 768;        // NN ints (contiguous w/ stats: one memset)
  const size_t o_rowptr = 100768;     // NN+1 ints
  const size_t o_buf0   = 200832;     // N*64 floats; msg1 [E]float2 pre-layer-2
  const size_t o_buf1   = 6600832;    // N*64 floats
  const size_t o_xh     = 13000832;   // N*64 fp16 (= 3.2M floats)
  const size_t o_agg1   = 16200832;   // N*2 floats (slim tier only)
  const size_t o_edat   = 16400832;   // packed: E uint4 | slim: E ints
  const size_t needA2 = (o_edat + (size_t)NE * 4) * 4;  // ~116.8 MB
  const size_t needA1 = (o_edat + (size_t)NE) * 4;      // ~78.4 MB
  const size_t needB  = (2 * 6600000 + 384) * 4;        // ~52.8 MB

  float* wsf = (float*)d_ws;

  if (ws_size >= needA1) {
    const bool packed = ws_size >= needA2;
    float* stats0 = wsf + o_stats;        // layer 1
    float* stats1 = wsf + o_stats + 256;  // layer 2
    float* stats2 = wsf + o_stats + 512;  // layer 3
    int* cnt     = (int*)(wsf + o_cnt);
    int* rowptr  = (int*)(wsf + o_rowptr);
    float* buf0  = wsf + o_buf0;
    float* buf1  = wsf + o_buf1;
    unsigned short* xh = (unsigned short*)(wsf + o_xh);
    float* agg1  = wsf + o_agg1;
    uint4* erec  = (uint4*)(wsf + o_edat);
    float* msg1  = buf0;  // [E]float2 == N*64 floats exactly; free until layer 2

    // ---- one memset covers stats(3 layers) + cnt ----
    hipMemsetAsync(wsf, 0, (768 + NN) * sizeof(float), stream);

    // ---- CSR build (once, shared by all 3 layers) ----
    count_kernel<<<4096, 256, 0, stream>>>(dstp, cnt);
    scan_kernel<<<1, 1024, 0, stream>>>(cnt, rowptr, cnt);
    if (packed)
      scatter2e_kernel<<<4096, 256, 0, stream>>>(srcp, dstp, ea, cnt, erec,
                                                 x, el1w, el1b, msg1);
    else
      scatter1_kernel<<<4096, 256, 0, stream>>>(dstp, cnt, (int*)(wsf + o_edat));

    // ---- layer 1 ----
    if (packed) {
      l1node_kernel<<<2048, 256, 0, stream>>>(rowptr, msg1, x, n1w1, n1b1,
                                              eps1, buf1, stats0);
    } else {
      l1agg_kernel<<<391, 256, 0, stream>>>(rowptr, (const int*)(wsf + o_edat),
                                            srcp, ea, x, el1w, el1b, agg1);
      nodeA2_kernel<<<2048, 256, 0, stream>>>(x, agg1, buf1, n1w1, n1b1, eps1,
                                              stats0);
    }
    nodeB_kernel<<<2048, 256, 0, stream>>>(buf1, buf1, n1w2, n1b2, stats0,
                                           n1g, n1bt, packed ? xh : nullptr);

    // ---- layers 2,3 (shared weights) ----
    if (packed) {
      gine64h_kernel<<<4096, 256, 0, stream>>>(rowptr, erec, buf1, xh,
                                               el2w, el2b, n2w1, n2b1, eps2,
                                               buf0, stats1);
      nodeB_kernel<<<2048, 256, 0, stream>>>(buf0, buf0, n2w2, n2b2, stats1,
                                             n2g, n2bt, xh);
      gine64h_kernel<<<4096, 256, 0, stream>>>(rowptr, erec, buf0, xh,
                                               el2w, el2b, n2w1, n2b1, eps2,
                                               buf1, stats2);
      nodeB_kernel<<<2048, 256, 0, stream>>>(buf1, buf1, n2w2, n2b2, stats2,
                                             n2g, n2bt, nullptr);
      final_kernel<<<(NN + 255) / 256, 256, 0, stream>>>(buf1, regw, regb, endw,
                                                         endb, (float*)d_out);
    } else {
      float* cur = buf1;
      float* wrk = buf0;
      float* sl[2] = {stats1, stats2};
      for (int l = 0; l < 2; l++) {
        gine64s_kernel<<<4096, 256, 0, stream>>>(rowptr, (const int*)(wsf + o_edat),
                                                 srcp, ea, cur, el2w, el2b, n2w1,
                                                 n2b1, eps2, wrk, sl[l]);
        nodeB_kernel<<<2048, 256, 0, stream>>>(wrk, wrk, n2w2, n2b2, sl[l],
                                               n2g, n2bt, nullptr);
        float* tmp = cur; cur = wrk; wrk = tmp;
      }
      final_kernel<<<(NN + 255) / 256, 256, 0, stream>>>(cur, regw, regb, endw,
                                                         endb, (float*)d_out);
    }
    return;
  }

  // ================= fallback tier B (round-1 proven path) =================
  if (ws_size < needB) return;
  const size_t BUF = 6600000;
  float* buf0 = (float*)d_ws;
  float* buf1 = buf0 + BUF;
  float* stats = buf1 + BUF;

  float* t1 = buf1;
  float* agg1 = buf1 + NN * 64;
  hipMemsetAsync(agg1, 0, NN * 2 * sizeof(float), stream);
  hipMemsetAsync(stats, 0, 128 * sizeof(double), stream);
  edge1_kernel<<<2048, 256, 0, stream>>>(x, ea, srcp, dstp, el1w, el1b, agg1);
  nodeA2_kernel<<<2048, 256, 0, stream>>>(x, agg1, t1, n1w1, n1b1, eps1, stats);
  nodeB_kernel<<<2048, 256, 0, stream>>>(t1, buf1, n1w2, n1b2, stats, n1g, n1bt,
                                         nullptr);

  float* cur = buf1;
  float* wrk = buf0;
  for (int l = 0; l < 2; l++) {
    hipMemsetAsync(wrk, 0, NN * 64 * sizeof(float), stream);
    hipMemsetAsync(stats, 0, 128 * sizeof(double), stream);
    edge64_kernel<<<2048, 256, 0, stream>>>(cur, ea, srcp, dstp, el2w, el2b, wrk);
    nodeA64_kernel<<<2048, 256, 0, stream>>>(cur, wrk, n2w1, n2b1, eps2, stats);
    nodeB_kernel<<<2048, 256, 0, stream>>>(wrk, wrk, n2w2, n2b2, stats, n2g, n2bt,
                                           nullptr);
    float* tmp = cur; cur = wrk; wrk = tmp;
  }

  final_kernel<<<(NN + 255) / 256, 256, 0, stream>>>(cur, regw, regb, endw, endb,
                                                     (float*)d_out);
}